// Round 13
// baseline (389.848 us; speedup 1.0000x reference)
//
#include <hip/hip_runtime.h>
#include <hip/hip_bf16.h>
#include <cstdint>
#include <cstddef>

typedef unsigned short u16;
typedef unsigned int   u32;
typedef short bf16x8 __attribute__((ext_vector_type(8)));   // 8 bf16 = 4 VGPRs
typedef float f32x4  __attribute__((ext_vector_type(4)));

// one 16-B record per sorted edge: {u|v<<16, 1/du, 1/dv, ie}
struct __align__(16) ERec { u32 uv; float iu, iv, ie; };
// one 8-B record per node
struct __align__(8) NRec { float dinv; float imp; };

#define NCOPY 8   // atomic privatization fan-out (blockIdx & 7)

__device__ __forceinline__ float bf2f(u16 v){ return __uint_as_float(((u32)v)<<16); }
__device__ __forceinline__ u16 f2bf(float f){
  u32 x = __float_as_uint(f);
  return (u16)((x + 0x7FFFu + ((x>>16)&1u)) >> 16);   // round-to-nearest-even
}
__device__ __forceinline__ void atomAddF(float* p, float v){ unsafeAtomicAdd(p, v); }
__device__ __forceinline__ float rlanef(float v, int q){
  return __int_as_float(__builtin_amdgcn_readlane(__float_as_int(v), q));
}

// ---------------- zero helper ----------------
__global__ void kzero(int* p, int n){
  int i = blockIdx.x*blockDim.x + threadIdx.x;
  if(i < n) p[i] = 0;
}

// ---------------- per-side degree counts + RANKS, 8-way privatized ----------
__global__ void kdeg2p(const int* __restrict__ ei0, const int* __restrict__ ei1,
                       int* __restrict__ deg0c, int* __restrict__ deg1c,
                       int* __restrict__ r0, int* __restrict__ r1,
                       int N, int E){
  int e = blockIdx.x*blockDim.x + threadIdx.x;
  if(e >= E) return;
  const int c = blockIdx.x & (NCOPY-1);
  r0[e] = atomicAdd(&deg0c[c*N + ei0[e]], 1);
  r1[e] = atomicAdd(&deg1c[c*N + ei1[e]], 1);
}

// ---------------- fold copies -> totals + per-copy base offsets ----------------
__global__ void kreduce(const int* __restrict__ deg0c, const int* __restrict__ deg1c,
                        int* __restrict__ deg0, int* __restrict__ deg1,
                        int* __restrict__ cb0, int* __restrict__ cb1, int N){
  int i = blockIdx.x*blockDim.x + threadIdx.x;
  if(i < N){
    int s = 0;
    #pragma unroll
    for(int c = 0; c < NCOPY; c++){ int t = deg0c[c*N+i]; cb0[c*N+i] = s; s += t; }
    deg0[i] = s;
  } else if(i < 2*N){
    int j = i - N;
    int s = 0;
    #pragma unroll
    for(int c = 0; c < NCOPY; c++){ int t = deg1c[c*N+j]; cb1[c*N+j] = s; s += t; }
    deg1[j] = s;
  }
}

// ---------------- hierarchical exclusive scan (3 phases) ----------------
__global__ __launch_bounds__(256) void ktilesum(const int* __restrict__ deg0,
                                                const int* __restrict__ deg1,
                                                int* __restrict__ tsum,
                                                int N, int nt){
  __shared__ int sh[256];
  const int b = blockIdx.x;
  const int* deg = (b < nt) ? deg0 : deg1;
  const int tile = (b < nt) ? b : b - nt;
  const int t = threadIdx.x;
  const int i = tile*256 + t;
  sh[t] = (i < N) ? deg[i] : 0;
  __syncthreads();
  for(int s = 128; s > 0; s >>= 1){
    if(t < s) sh[t] += sh[t+s];
    __syncthreads();
  }
  if(t == 0) tsum[b] = sh[0];
}
__global__ __launch_bounds__(256) void kmid(int* __restrict__ tsum,
                                            int* __restrict__ off0,
                                            int* __restrict__ off1,
                                            int N, int nt){
  __shared__ int sh[256];
  const int b = blockIdx.x;
  int* ts = tsum + b*nt;
  const int t = threadIdx.x;
  sh[t] = (t < nt) ? ts[t] : 0;
  __syncthreads();
  for(int s = 1; s < 256; s <<= 1){
    int x = (t >= s) ? sh[t-s] : 0;
    __syncthreads();
    sh[t] += x;
    __syncthreads();
  }
  if(t < nt) ts[t] = (t == 0) ? 0 : sh[t-1];
  if(t == 255){ int* off = b ? off1 : off0; off[N] = sh[255]; }
}
// phase 3: intra-tile scan + tile base -> off[]; blocks b<nt also emit NRec
__global__ __launch_bounds__(256) void kapply(const int* __restrict__ deg0,
                                              const int* __restrict__ deg1,
                                              const int* __restrict__ tsum,
                                              int* __restrict__ off0,
                                              int* __restrict__ off1,
                                              const float* __restrict__ nimp,
                                              NRec* __restrict__ nrec,
                                              int N, int nt){
  __shared__ int sh[256];
  const int b = blockIdx.x;
  const int* deg = (b < nt) ? deg0 : deg1;
  int*       off = (b < nt) ? off0 : off1;
  const int tile = (b < nt) ? b : b - nt;
  const int base = tsum[b];
  const int t = threadIdx.x;
  const int i = tile*256 + t;
  sh[t] = (i < N) ? deg[i] : 0;
  __syncthreads();
  for(int s = 1; s < 256; s <<= 1){
    int x = (t >= s) ? sh[t-s] : 0;
    __syncthreads();
    sh[t] += x;
    __syncthreads();
  }
  if(i < N){
    off[i] = base + ((t == 0) ? 0 : sh[t-1]);
    if(b < nt){
      int d = deg0[i] + deg1[i];
      NRec r;
      r.dinv = (d > 1) ? (1.f/(float)d) : 0.f;   // deg==1 hyperedges dropped
      r.imp  = nimp[i];
      nrec[i] = r;
    }
  }
}

// ---------------- placement: ATOMIC-FREE (ranks precomputed) ----------------
__global__ void kpermv(const int* __restrict__ ei0, const int* __restrict__ ei1,
                       const NRec* __restrict__ nrec,
                       const int* __restrict__ off0, const int* __restrict__ off1,
                       const int* __restrict__ cb0, const int* __restrict__ cb1,
                       const int* __restrict__ r0, const int* __restrict__ r1,
                       ERec* __restrict__ rec, int* __restrict__ orig,
                       int* __restrict__ list1, int E, int N){
  int e = blockIdx.x*blockDim.x + threadIdx.x;
  if(e >= E) return;
  const int c = blockIdx.x & (NCOPY-1);      // must match kdeg2p's mapping
  int u = ei0[e], v = ei1[e];
  NRec ru = nrec[u];
  NRec rv = nrec[v];
  int pos = off0[u] + cb0[c*N+u] + r0[e];
  float ie = fminf(ru.imp, rv.imp);
  ERec r;
  r.uv = (u32)u | ((u32)v << 16);
  r.iu = ru.dinv; r.iv = rv.dinv; r.ie = ie;
  rec[pos]  = r;          // 16-B scattered store (one dwordx4)
  orig[pos] = e;          // scattered 4B (pos -> original edge)
  int p1 = off1[v] + cb1[c*N+v] + r1[e];
  list1[p1] = pos;        // scattered 4B
}

// ---------------- h0 = edge_attr * imp, bf16, SORTED order --------------------
__global__ __launch_bounds__(256) void kprep0(const float* __restrict__ ea,
                                              const int* __restrict__ orig,
                                              const float* __restrict__ recf, // (const float*)rec
                                              u16* __restrict__ h0, int E){
  int idx = blockIdx.x*256 + threadIdx.x;
  int row = idx >> 2;
  int c   = (idx & 3)*8;
  if(row >= E) return;
  int oe = orig[row];
  float ie = recf[(size_t)row*4 + 3];           // ERec.ie
  const float* s = ea + (size_t)oe*32 + c;
  f32x4 v0 = *(const f32x4*)s;
  f32x4 v1 = *(const f32x4*)(s+4);
  u32 o0 = (u32)f2bf(v0.x*ie) | ((u32)f2bf(v0.y*ie) << 16);
  u32 o1 = (u32)f2bf(v0.z*ie) | ((u32)f2bf(v0.w*ie) << 16);
  u32 o2 = (u32)f2bf(v1.x*ie) | ((u32)f2bf(v1.y*ie) << 16);
  u32 o3 = (u32)f2bf(v1.z*ie) | ((u32)f2bf(v1.w*ie) << 16);
  *(uint4*)(h0 + (size_t)row*32 + c) = make_uint4(o0,o1,o2,o3);
}

// ---------------- W -> fragment-ready layout (all 3 layers, one launch) -------
__global__ void kprepw(const float* __restrict__ W0, u16* __restrict__ wf0,
                       const float* __restrict__ W1, u16* __restrict__ wf1,
                       const float* __restrict__ W2, u16* __restrict__ wf2){
  const int b = blockIdx.x;
  const float* W; u16* wf; int NC, sbase;
  if(b == 0){ W = W0; wf = wf0; NC = 1; sbase = 0; }
  else if(b <= 2){ W = W1; wf = wf1; NC = 2; sbase = (b-1)*256; }
  else { W = W2; wf = wf2; NC = 2; sbase = (b-3)*256; }
  int s = sbase + threadIdx.x;
  if(s >= 4*NC*64) return;
  int lane = s & 63;
  int c    = (s >> 6) % NC;
  int tt   = s / (NC*64);
  int n  = tt*16 + (lane & 15);
  int k0 = c*32 + (lane >> 4)*8;
  #pragma unroll
  for(int j = 0; j < 8; j++)
    wf[(size_t)s*8 + j] = f2bf(W[(size_t)(k0 + j)*64 + n]);
}

// ---------------- aggregate (templated on row dim) ----------------------------
template<int DIM>
__global__ __launch_bounds__(256) void kagg(const u16* __restrict__ buf,
                                            const int* __restrict__ off0,
                                            const int* __restrict__ off1,
                                            const int* __restrict__ list1,
                                            u16* __restrict__ heb, int N){
  const int t = threadIdx.x, wv = t >> 6, lane = t & 63;
  const int n = blockIdx.x*4 + wv;
  if(n >= N) return;
  constexpr int CB = DIM/8;       // col-blocks (8 cols each)
  constexpr int RS = 64/CB;       // rows per wave-instr
  const int rsub = lane / CB, cb = lane % CB;
  float acc[8];
  #pragma unroll
  for(int k = 0; k < 8; k++) acc[k] = 0.f;

  auto accum = [&](uint4 x){
    acc[0] += bf2f((u16)x.x); acc[1] += bf2f((u16)(x.x>>16));
    acc[2] += bf2f((u16)x.y); acc[3] += bf2f((u16)(x.y>>16));
    acc[4] += bf2f((u16)x.z); acc[5] += bf2f((u16)(x.z>>16));
    acc[6] += bf2f((u16)x.w); acc[7] += bf2f((u16)(x.w>>16));
  };
  const uint4 zero4 = {0,0,0,0};

  // u-side: contiguous rows [off0[n], off0[n+1])
  {
    const int s0 = off0[n], d0 = off0[n+1] - s0;
    const u16* base = buf + (size_t)s0*DIM;
    int j = 0;
    for(; j + RS <= d0; j += RS)
      accum(*(const uint4*)(base + (size_t)(j+rsub)*DIM + cb*8));
    if(j < d0)
      accum((rsub < d0-j) ? *(const uint4*)(base + (size_t)(j+rsub)*DIM + cb*8) : zero4);
  }
  // v-side: random rows via list1
  {
    const int s1 = off1[n], d1 = off1[n+1] - s1;
    int j = 0;
    for(; j + RS <= d1; j += RS){
      int e = list1[s1 + j + rsub];
      accum(*(const uint4*)(buf + (size_t)e*DIM + cb*8));
    }
    if(j < d1){
      uint4 x = zero4;
      if(rsub < d1-j){
        int e = list1[s1 + j + rsub];
        x = *(const uint4*)(buf + (size_t)e*DIM + cb*8);
      }
      accum(x);
    }
  }
  // reduce across rsub
  #pragma unroll
  for(int m = CB; m <= 32; m <<= 1)
    #pragma unroll
    for(int k = 0; k < 8; k++) acc[k] += __shfl_xor(acc[k], m);
  if(rsub == 0){
    u32 o[4];
    #pragma unroll
    for(int k = 0; k < 4; k++)
      o[k] = (u32)f2bf(acc[2*k]) | ((u32)f2bf(acc[2*k+1]) << 16);
    *(uint4*)(heb + (size_t)n*DIM + cb*8) = make_uint4(o[0],o[1],o[2],o[3]);
  }
}

// ---------------- gather bank for kfusedR1 (24 loads/lane) --------------------
__device__ __forceinline__ void issueR1(const u16* __restrict__ h0r,
                                        const u16* __restrict__ agg0,
                                        u32 uvp, int c32, int half,
                                        u16 (&zb)[8], u16 (&hu)[8], u16 (&hv)[8]){
  #pragma unroll
  for(int q = 0; q < 8; q++){
    const u32 uvA = (u32)__builtin_amdgcn_readlane((int)uvp, 2*q);
    const u32 uvB = (u32)__builtin_amdgcn_readlane((int)uvp, 2*q+1);
    const u32 uvS = half ? uvB : uvA;
    hv[q] = agg0[(size_t)(uvS >> 16)*32 + c32];
    hu[q] = agg0[(size_t)(uvS & 0xffffu)*32 + c32];
    zb[q] = h0r[(2*q+half)*32 + c32];
  }
}

// ---------------- layer 1 fused: combine(32) -> @W0 -> epilogue -> @W1 --------
// Depth-2 gather pipeline (24 loads/bank -> 48 in flight < 63 VMEM queue):
// issue(G0), issue(G1), consume(G0), issue(G2), consume(G1), issue(G3),
// consume(G2), consume(G3). All 4 descriptor banks loaded up-front.
__global__ __launch_bounds__(256, 3) void kfusedR1(const u16* __restrict__ h0,
                                                   const u16* __restrict__ agg0,
                                                   u16* __restrict__ buf,
                                                   const f32x4* __restrict__ rec4,
                                                   const int* __restrict__ batch,
                                                   const float* __restrict__ bias0,
                                                   const u16* __restrict__ wf0,
                                                   const u16* __restrict__ wf1,
                                                   float* __restrict__ gh0,
                                                   int E){
  __shared__ __align__(16) u16 hT[4*16*72];
  __shared__ float ies[4][16];
  const int t = threadIdx.x, wv = t >> 6, lane = t & 63;
  const int quad = lane >> 4, l15 = lane & 15;
  const int c32  = lane & 31;
  const int half = lane >> 5;
  u16* hTw = &hT[wv*1152];

  float bd4[4];
  #pragma unroll
  for(int tt = 0; tt < 4; tt++) bd4[tt] = bias0[tt*16 + l15];

  bf16x8 b0fr[4];
  #pragma unroll
  for(int i = 0; i < 4; i++)
    b0fr[i] = *(const bf16x8*)(wf0 + ((size_t)i*64 + lane)*8);
  bf16x8 b1fr[8];
  #pragma unroll
  for(int i = 0; i < 8; i++)
    b1fr[i] = *(const bf16x8*)(wf1 + ((size_t)i*64 + lane)*8);

  float pool[4] = {0.f,0.f,0.f,0.f};
  int cur_g = -1;
  const int base = __builtin_amdgcn_readfirstlane((int)(blockIdx.x*256) + wv*64);

  auto flushPool = [&](){
    #pragma unroll
    for(int tt = 0; tt < 4; tt++){
      float s = pool[tt];
      s += __shfl_xor(s, 16);
      s += __shfl_xor(s, 32);
      if(quad == 0) atomAddF(&gh0[cur_g*192 + tt*16 + l15], s);
      pool[tt] = 0.f;
    }
  };

  // ---- all 4 descriptor banks up-front (lane l15 holds edge rk+l15) ----
  u32 uv_[4]; f32x4 cf_[4]; int bt_[4];
  #pragma unroll
  for(int k = 0; k < 4; k++){
    uv_[k] = 0; cf_[k] = (f32x4){0.f,0.f,0.f,0.f}; bt_[k] = 0;
    const int rk = base + k*16;
    if(rk < E){
      f32x4 w0 = rec4[(size_t)(rk+l15)];
      uv_[k] = __float_as_uint(w0.x);
      const float iu = w0.y, iv = w0.z;
      const float rc = (iu > 0.f && iv > 0.f) ? (1.f/3.f)
                     : ((iu > 0.f || iv > 0.f) ? 0.5f : 1.f);
      cf_[k].x = rc; cf_[k].y = iu*rc; cf_[k].z = iv*rc; cf_[k].w = w0.w;
      bt_[k] = batch[uv_[k] & 0xffffu];
    }
  }

  auto consume = [&](int r0, f32x4 cf, int bt,
                     u16 (&zb)[8], u16 (&hu)[8], u16 (&hv)[8]){
    // ---- publish ie per row for fragment epilogue ----
    if(lane < 16) ies[wv][lane] = cf.w;
    // ---- combine -> z (bf16) into LDS, all 64 lanes, 8 iterations ----
    #pragma unroll
    for(int q = 0; q < 8; q++){
      const float rcA = rlanef(cf.x, 2*q), rcB = rlanef(cf.x, 2*q+1);
      const float iuA = rlanef(cf.y, 2*q), iuB = rlanef(cf.y, 2*q+1);
      const float ivA = rlanef(cf.z, 2*q), ivB = rlanef(cf.z, 2*q+1);
      const float rc   = half ? rcB : rcA;
      const float iurc = half ? iuB : iuA;
      const float ivrc = half ? ivB : ivA;
      float z = fmaf(bf2f(zb[q]), rc,
                fmaf(bf2f(hu[q]), iurc, bf2f(hv[q])*ivrc));
      hTw[(2*q+half)*72 + c32] = f2bf(z);
    }
    // ---- MFMA1: z @ W0 (K=32) ----
    bf16x8 za = *(const bf16x8*)&hTw[l15*72 + quad*8];
    f32x4 a0_[4];
    #pragma unroll
    for(int tt = 0; tt < 4; tt++){
      f32x4 a = {0.f,0.f,0.f,0.f};
      a = __builtin_amdgcn_mfma_f32_16x16x32_bf16(za, b0fr[tt], a, 0, 0, 0);
      a0_[tt] = a;
    }
    // ---- fragment epilogue: h1 = relu(a + b0) * ie[row] ----
    float ier[4];
    #pragma unroll
    for(int r = 0; r < 4; r++) ier[r] = ies[wv][quad*4 + r];
    float o[4][4];
    #pragma unroll
    for(int tt = 0; tt < 4; tt++)
      #pragma unroll
      for(int r = 0; r < 4; r++)
        o[tt][r] = fmaxf(a0_[tt][r] + bd4[tt], 0.f) * ier[r];
    // ---- pool gh0 ----
    const int bFirst = __builtin_amdgcn_readlane(bt, 0);
    const int bLast  = __builtin_amdgcn_readlane(bt, 15);
    if(bFirst == bLast){
      if(bFirst != cur_g){
        if(cur_g >= 0) flushPool();
        cur_g = bFirst;
      }
      #pragma unroll
      for(int tt = 0; tt < 4; tt++)
        pool[tt] += (o[tt][0] + o[tt][1]) + (o[tt][2] + o[tt][3]);
    } else {
      #pragma unroll
      for(int rr = 0; rr < 16; rr++){
        const int bq = __builtin_amdgcn_readlane(bt, rr);
        if(bq != cur_g){
          if(cur_g >= 0) flushPool();
          cur_g = bq;
        }
        if((rr >> 2) == quad){
          #pragma unroll
          for(int tt = 0; tt < 4; tt++) pool[tt] += o[tt][rr & 3];
        }
      }
    }
    // ---- h1 -> LDS [16][72] full 64 cols ----
    #pragma unroll
    for(int tt = 0; tt < 4; tt++)
      #pragma unroll
      for(int r = 0; r < 4; r++)
        hTw[(quad*4 + r)*72 + tt*16 + l15] = f2bf(o[tt][r]);
    // ---- MFMA2: h1 @ W1 (K=64) -> buf (xw2) ----
    bf16x8 afr0 = *(const bf16x8*)&hTw[l15*72 + quad*8];
    bf16x8 afr1 = *(const bf16x8*)&hTw[l15*72 + 32 + quad*8];
    #pragma unroll
    for(int tt = 0; tt < 4; tt++){
      f32x4 a = {0.f,0.f,0.f,0.f};
      a = __builtin_amdgcn_mfma_f32_16x16x32_bf16(afr0, b1fr[tt*2+0], a, 0, 0, 0);
      a = __builtin_amdgcn_mfma_f32_16x16x32_bf16(afr1, b1fr[tt*2+1], a, 0, 0, 0);
      const int n = tt*16 + l15;
      #pragma unroll
      for(int r = 0; r < 4; r++)
        buf[(size_t)(r0 + quad*4 + r)*64 + n] = f2bf(a[r]);
    }
  };

  const int r0b = base, r1b = base+16, r2b = base+32, r3b = base+48;
  const bool a0 = r0b < E, a1 = r1b < E, a2 = r2b < E, a3 = r3b < E;

  u16 zbA[8], huA[8], hvA[8];
  u16 zbB[8], huB[8], hvB[8];

  if(a0) issueR1(h0 + (size_t)r0b*32, agg0, uv_[0], c32, half, zbA, huA, hvA);
  if(a1) issueR1(h0 + (size_t)r1b*32, agg0, uv_[1], c32, half, zbB, huB, hvB);
  if(a0) consume(r0b, cf_[0], bt_[0], zbA, huA, hvA);
  if(a2) issueR1(h0 + (size_t)r2b*32, agg0, uv_[2], c32, half, zbA, huA, hvA);
  if(a1) consume(r1b, cf_[1], bt_[1], zbB, huB, hvB);
  if(a3) issueR1(h0 + (size_t)r3b*32, agg0, uv_[3], c32, half, zbB, huB, hvB);
  if(a2) consume(r2b, cf_[2], bt_[2], zbA, huA, hvA);
  if(a3) consume(r3b, cf_[3], bt_[3], zbB, huB, hvB);

  if(cur_g >= 0) flushPool();
}

// ---------------- fused L2/L3: gather + epilogue + register-pool (+ GEMM) -----
template<bool DO_GEMM>
__global__ __launch_bounds__(256, 3) void kfused(u16* __restrict__ buf,   // r/w
                                                 const u16* __restrict__ heb,
                                                 const f32x4* __restrict__ rec4,
                                                 const int* __restrict__ batch,
                                                 const float* __restrict__ bias,
                                                 const u16* __restrict__ wf,
                                                 float* __restrict__ ghL,
                                                 int E){
  constexpr int HTSZ = DO_GEMM ? 4*16*72 : 4;
  __shared__ __align__(16) u16 hT[HTSZ];
  const int t = threadIdx.x, wv = t >> 6, lane = t & 63;
  const int quad = lane >> 4, l15 = lane & 15;
  const float bd = bias[lane];

  bf16x8 bfr[8];
  if(DO_GEMM){
    #pragma unroll
    for(int i = 0; i < 8; i++)
      bfr[i] = *(const bf16x8*)(wf + ((size_t)i*64 + lane)*8);
  }

  float pool = 0.f;
  int cur_g = -1;
  const int base = __builtin_amdgcn_readfirstlane((int)(blockIdx.x*256) + wv*64);
  u16* hTw = DO_GEMM ? &hT[wv*1152] : &hT[0];

  u32 uvp = 0; f32x4 cf = {0.f,0.f,0.f,0.f}; int bt = 0;
  if(base < E){
    f32x4 w0 = rec4[(size_t)(base+l15)];
    uvp = __float_as_uint(w0.x);
    const float iu = w0.y, iv = w0.z;
    const float rc = (iu > 0.f && iv > 0.f) ? (1.f/3.f)
                   : ((iu > 0.f || iv > 0.f) ? 0.5f : 1.f);
    cf.x = rc; cf.y = iu*rc; cf.z = iv*rc; cf.w = w0.w;
    bt  = batch[uvp & 0xffffu];
  }

  #pragma unroll
  for(int it = 0; it < 4; it++){
    const int r0 = base + it*16;
    if(r0 < E){
      u16 bv[16], hu[16], hv[16];
      const u16* bufr = buf + (size_t)r0*64;
      #pragma unroll
      for(int q = 0; q < 16; q++){
        const u32 uv = (u32)__builtin_amdgcn_readlane((int)uvp, q);
        hv[q] = heb[(size_t)(uv >> 16)*64 + lane];
        hu[q] = heb[(size_t)(uv & 0xffffu)*64 + lane];
        bv[q] = bufr[q*64 + lane];
      }
      u32 uvpN = uvp; f32x4 cfN = cf; int btN = bt;
      if(it < 3){
        const int r1 = r0 + 16;
        if(r1 < E){
          f32x4 w0 = rec4[(size_t)(r1+l15)];
          uvpN = __float_as_uint(w0.x);
          const float iu = w0.y, iv = w0.z;
          const float rc = (iu > 0.f && iv > 0.f) ? (1.f/3.f)
                         : ((iu > 0.f || iv > 0.f) ? 0.5f : 1.f);
          cfN.x = rc; cfN.y = iu*rc; cfN.z = iv*rc; cfN.w = w0.w;
          btN  = batch[uvpN & 0xffffu];
        }
      }
      const int bFirst = __builtin_amdgcn_readlane(bt, 0);
      const int bLast  = __builtin_amdgcn_readlane(bt, 15);
      if(bFirst != cur_g){
        if(cur_g >= 0) atomAddF(&ghL[cur_g*192 + lane], pool);
        pool = 0.f; cur_g = bFirst;
      }
      if(bFirst == bLast){
        #pragma unroll
        for(int q = 0; q < 16; q++){
          const float rc   = rlanef(cf.x, q);
          const float iurc = rlanef(cf.y, q);
          const float ivrc = rlanef(cf.z, q);
          const float ie   = rlanef(cf.w, q);
          float o = fmaxf(fmaf(bf2f(bv[q]), rc,
                          fmaf(bf2f(hu[q]), iurc,
                          fmaf(bf2f(hv[q]), ivrc, bd))), 0.f) * ie;
          pool += o;
          if(DO_GEMM) hTw[q*72 + lane] = f2bf(o);
        }
      } else {
        #pragma unroll
        for(int q = 0; q < 16; q++){
          const float rc   = rlanef(cf.x, q);
          const float iurc = rlanef(cf.y, q);
          const float ivrc = rlanef(cf.z, q);
          const float ie   = rlanef(cf.w, q);
          const int   bq   = __builtin_amdgcn_readlane(bt, q);
          float o = fmaxf(fmaf(bf2f(bv[q]), rc,
                          fmaf(bf2f(hu[q]), iurc,
                          fmaf(bf2f(hv[q]), ivrc, bd))), 0.f) * ie;
          if(bq != cur_g){
            if(cur_g >= 0) atomAddF(&ghL[cur_g*192 + lane], pool);
            pool = 0.f; cur_g = bq;
          }
          pool += o;
          if(DO_GEMM) hTw[q*72 + lane] = f2bf(o);
        }
      }
      if(DO_GEMM){
        bf16x8 afr0 = *(const bf16x8*)&hTw[l15*72 + quad*8];
        bf16x8 afr1 = *(const bf16x8*)&hTw[l15*72 + 32 + quad*8];
        #pragma unroll
        for(int tt = 0; tt < 4; tt++){
          f32x4 a = {0.f,0.f,0.f,0.f};
          a = __builtin_amdgcn_mfma_f32_16x16x32_bf16(afr0, bfr[tt*2+0], a, 0, 0, 0);
          a = __builtin_amdgcn_mfma_f32_16x16x32_bf16(afr1, bfr[tt*2+1], a, 0, 0, 0);
          const int n = tt*16 + l15;
          #pragma unroll
          for(int r = 0; r < 4; r++)
            buf[(size_t)(r0 + quad*4 + r)*64 + n] = f2bf(a[r]);
        }
      }
      uvp = uvpN; cf = cfN; bt = btN;
    }
  }
  if(cur_g >= 0) atomAddF(&ghL[cur_g*192 + lane], pool);
}

__global__ void kfinal(const float* __restrict__ gh, float* __restrict__ out, int n){
  int i = blockIdx.x*blockDim.x + threadIdx.x;
  if(i < n) out[i] = gh[i];   // reference output dtype = float32
}

// ---------------- host ----------------
extern "C" void kernel_launch(void* const* d_in, const int* in_sizes, int n_in,
                              void* d_out, int out_size, void* d_ws, size_t ws_size,
                              hipStream_t stream) {
  const float* edge_attr = (const float*)d_in[1];
  const int*   ei        = (const int*)d_in[2];
  const int*   batch     = (const int*)d_in[3];
  const float* nimp      = (const float*)d_in[4];
  const float* Ws[3] = { (const float*)d_in[5], (const float*)d_in[7], (const float*)d_in[9] };
  const float* bs[3] = { (const float*)d_in[6], (const float*)d_in[8], (const float*)d_in[10] };

  const int E = in_sizes[1] / 32;   // edge_attr is (E, 32)
  const int N = in_sizes[4];        // node_imp is (N,)
  const int* ei0 = ei;
  const int* ei1 = ei + E;

  char* p = (char*)d_ws;
  auto carve = [&](size_t bytes)->char*{
    char* r = p; p += (bytes + 255) & ~(size_t)255; return r;
  };
  const int nt = (N + 255)/256;
  int*   deg0c = (int*)  carve((size_t)2*NCOPY*N*4);
  int*   deg1c = deg0c + NCOPY*N;
  int*   cb0   = (int*)  carve((size_t)2*NCOPY*N*4);
  int*   cb1   = cb0 + NCOPY*N;
  int*   r0    = (int*)  carve((size_t)2*E*4);       // per-edge ranks
  int*   r1    = r0 + E;
  int*   deg0  = (int*)  carve((size_t)2*N*4);
  int*   deg1  = deg0 + N;
  NRec*  nrec  = (NRec*) carve((size_t)N*sizeof(NRec));
  int*   off0  = (int*)  carve((size_t)(N+1)*4);
  int*   off1  = (int*)  carve((size_t)(N+1)*4);
  int*   tsum  = (int*)  carve((size_t)2*nt*4);
  int*   orig  = (int*)  carve((size_t)E*4);
  int*   list1 = (int*)  carve((size_t)E*4);
  ERec*  rec   = (ERec*) carve((size_t)E*sizeof(ERec));
  u16*   h0    = (u16*)  carve((size_t)E*32*2);      // layer-1 input, sorted
  u16*   agg0  = (u16*)  carve((size_t)N*32*2);
  u16*   heb   = (u16*)  carve((size_t)N*64*2);
  u16*   buf   = (u16*)  carve((size_t)E*64*2);      // xw2 / xw3 in-place
  float* gh    = (float*)carve((size_t)64*192*4);
  u16*   wfs[3];
  for(int l = 0; l < 3; l++) wfs[l] = (u16*)carve((size_t)4096*2);

  kzero<<<(2*NCOPY*N+255)/256, 256, 0, stream>>>(deg0c, 2*NCOPY*N);
  kzero<<<(12288+255)/256, 256, 0, stream>>>((int*)gh, 12288);
  kdeg2p<<<(E+255)/256, 256, 0, stream>>>(ei0, ei1, deg0c, deg1c, r0, r1, N, E);
  kreduce<<<(2*N+255)/256, 256, 0, stream>>>(deg0c, deg1c, deg0, deg1, cb0, cb1, N);
  ktilesum<<<2*nt, 256, 0, stream>>>(deg0, deg1, tsum, N, nt);
  kmid<<<2, 256, 0, stream>>>(tsum, off0, off1, N, nt);
  kapply<<<2*nt, 256, 0, stream>>>(deg0, deg1, tsum, off0, off1, nimp, nrec, N, nt);
  kpermv<<<(E+255)/256, 256, 0, stream>>>(ei0, ei1, nrec, off0, off1, cb0, cb1,
                                          r0, r1, rec, orig, list1, E, N);
  kprep0<<<((E*4)+255)/256, 256, 0, stream>>>(edge_attr, orig, (const float*)rec, h0, E);
  kprepw<<<5, 256, 0, stream>>>(Ws[0], wfs[0], Ws[1], wfs[1], Ws[2], wfs[2]);

  const int nbA = (N + 3)/4;
  const int nbF = (E + 255)/256;   // contiguous 256-edge chunk per block

  kagg<32><<<nbA, 256, 0, stream>>>(h0, off0, off1, list1, agg0, N);
  kfusedR1<<<nbF, 256, 0, stream>>>(h0, agg0, buf, (const f32x4*)rec, batch,
                                    bs[0], wfs[0], wfs[1], gh + 0*64, E);
  kagg<64><<<nbA, 256, 0, stream>>>(buf, off0, off1, list1, heb, N);
  kfused<true ><<<nbF, 256, 0, stream>>>(buf, heb, (const f32x4*)rec, batch, bs[1], wfs[2], gh + 1*64, E);
  kagg<64><<<nbA, 256, 0, stream>>>(buf, off0, off1, list1, heb, N);
  kfused<false><<<nbF, 256, 0, stream>>>(buf, heb, (const f32x4*)rec, batch, bs[2], nullptr, gh + 2*64, E);
  kfinal<<<(12288+255)/256, 256, 0, stream>>>(gh, (float*)d_out, 12288);
}

// Round 14
// 379.386 us; speedup vs baseline: 1.0276x; 1.0276x over previous
//
#include <hip/hip_runtime.h>
#include <hip/hip_bf16.h>
#include <cstdint>
#include <cstddef>

typedef unsigned short u16;
typedef unsigned int   u32;
typedef short bf16x8 __attribute__((ext_vector_type(8)));   // 8 bf16 = 4 VGPRs
typedef float f32x4  __attribute__((ext_vector_type(4)));

// one 16-B record per sorted edge: {u|v<<16, 1/du, 1/dv, ie}
struct __align__(16) ERec { u32 uv; float iu, iv, ie; };
// one 8-B record per node
struct __align__(8) NRec { float dinv; float imp; };

#define NCOPY 8   // atomic privatization fan-out (blockIdx & 7)

__device__ __forceinline__ float bf2f(u16 v){ return __uint_as_float(((u32)v)<<16); }
__device__ __forceinline__ u16 f2bf(float f){
  u32 x = __float_as_uint(f);
  return (u16)((x + 0x7FFFu + ((x>>16)&1u)) >> 16);   // round-to-nearest-even
}
__device__ __forceinline__ void atomAddF(float* p, float v){ unsafeAtomicAdd(p, v); }
__device__ __forceinline__ float rlanef(float v, int q){
  return __int_as_float(__builtin_amdgcn_readlane(__float_as_int(v), q));
}

// ---------------- zero helper ----------------
__global__ void kzero(int* p, int n){
  int i = blockIdx.x*blockDim.x + threadIdx.x;
  if(i < n) p[i] = 0;
}

// ---------------- per-side degree counts + RANKS, 8-way privatized ----------
__global__ void kdeg2p(const int* __restrict__ ei0, const int* __restrict__ ei1,
                       int* __restrict__ deg0c, int* __restrict__ deg1c,
                       int* __restrict__ r0, int* __restrict__ r1,
                       int N, int E){
  int e = blockIdx.x*blockDim.x + threadIdx.x;
  if(e >= E) return;
  const int c = blockIdx.x & (NCOPY-1);
  r0[e] = atomicAdd(&deg0c[c*N + ei0[e]], 1);
  r1[e] = atomicAdd(&deg1c[c*N + ei1[e]], 1);
}

// ---------------- fold copies -> totals + per-copy base offsets ----------------
__global__ void kreduce(const int* __restrict__ deg0c, const int* __restrict__ deg1c,
                        int* __restrict__ deg0, int* __restrict__ deg1,
                        int* __restrict__ cb0, int* __restrict__ cb1, int N){
  int i = blockIdx.x*blockDim.x + threadIdx.x;
  if(i < N){
    int s = 0;
    #pragma unroll
    for(int c = 0; c < NCOPY; c++){ int t = deg0c[c*N+i]; cb0[c*N+i] = s; s += t; }
    deg0[i] = s;
  } else if(i < 2*N){
    int j = i - N;
    int s = 0;
    #pragma unroll
    for(int c = 0; c < NCOPY; c++){ int t = deg1c[c*N+j]; cb1[c*N+j] = s; s += t; }
    deg1[j] = s;
  }
}

// ---------------- hierarchical exclusive scan (3 phases) ----------------
__global__ __launch_bounds__(256) void ktilesum(const int* __restrict__ deg0,
                                                const int* __restrict__ deg1,
                                                int* __restrict__ tsum,
                                                int N, int nt){
  __shared__ int sh[256];
  const int b = blockIdx.x;
  const int* deg = (b < nt) ? deg0 : deg1;
  const int tile = (b < nt) ? b : b - nt;
  const int t = threadIdx.x;
  const int i = tile*256 + t;
  sh[t] = (i < N) ? deg[i] : 0;
  __syncthreads();
  for(int s = 128; s > 0; s >>= 1){
    if(t < s) sh[t] += sh[t+s];
    __syncthreads();
  }
  if(t == 0) tsum[b] = sh[0];
}
__global__ __launch_bounds__(256) void kmid(int* __restrict__ tsum,
                                            int* __restrict__ off0,
                                            int* __restrict__ off1,
                                            int N, int nt){
  __shared__ int sh[256];
  const int b = blockIdx.x;
  int* ts = tsum + b*nt;
  const int t = threadIdx.x;
  sh[t] = (t < nt) ? ts[t] : 0;
  __syncthreads();
  for(int s = 1; s < 256; s <<= 1){
    int x = (t >= s) ? sh[t-s] : 0;
    __syncthreads();
    sh[t] += x;
    __syncthreads();
  }
  if(t < nt) ts[t] = (t == 0) ? 0 : sh[t-1];
  if(t == 255){ int* off = b ? off1 : off0; off[N] = sh[255]; }
}
// phase 3: intra-tile scan + tile base -> off[]; blocks b<nt also emit NRec
__global__ __launch_bounds__(256) void kapply(const int* __restrict__ deg0,
                                              const int* __restrict__ deg1,
                                              const int* __restrict__ tsum,
                                              int* __restrict__ off0,
                                              int* __restrict__ off1,
                                              const float* __restrict__ nimp,
                                              NRec* __restrict__ nrec,
                                              int N, int nt){
  __shared__ int sh[256];
  const int b = blockIdx.x;
  const int* deg = (b < nt) ? deg0 : deg1;
  int*       off = (b < nt) ? off0 : off1;
  const int tile = (b < nt) ? b : b - nt;
  const int base = tsum[b];
  const int t = threadIdx.x;
  const int i = tile*256 + t;
  sh[t] = (i < N) ? deg[i] : 0;
  __syncthreads();
  for(int s = 1; s < 256; s <<= 1){
    int x = (t >= s) ? sh[t-s] : 0;
    __syncthreads();
    sh[t] += x;
    __syncthreads();
  }
  if(i < N){
    off[i] = base + ((t == 0) ? 0 : sh[t-1]);
    if(b < nt){
      int d = deg0[i] + deg1[i];
      NRec r;
      r.dinv = (d > 1) ? (1.f/(float)d) : 0.f;   // deg==1 hyperedges dropped
      r.imp  = nimp[i];
      nrec[i] = r;
    }
  }
}

// ---------------- placement: ATOMIC-FREE (ranks precomputed) ----------------
__global__ void kpermv(const int* __restrict__ ei0, const int* __restrict__ ei1,
                       const NRec* __restrict__ nrec,
                       const int* __restrict__ off0, const int* __restrict__ off1,
                       const int* __restrict__ cb0, const int* __restrict__ cb1,
                       const int* __restrict__ r0, const int* __restrict__ r1,
                       ERec* __restrict__ rec, int* __restrict__ orig,
                       int* __restrict__ list1, int E, int N){
  int e = blockIdx.x*blockDim.x + threadIdx.x;
  if(e >= E) return;
  const int c = blockIdx.x & (NCOPY-1);      // must match kdeg2p's mapping
  int u = ei0[e], v = ei1[e];
  NRec ru = nrec[u];
  NRec rv = nrec[v];
  int pos = off0[u] + cb0[c*N+u] + r0[e];
  float ie = fminf(ru.imp, rv.imp);
  ERec r;
  r.uv = (u32)u | ((u32)v << 16);
  r.iu = ru.dinv; r.iv = rv.dinv; r.ie = ie;
  rec[pos]  = r;          // 16-B scattered store (one dwordx4)
  orig[pos] = e;          // scattered 4B (pos -> original edge)
  int p1 = off1[v] + cb1[c*N+v] + r1[e];
  list1[p1] = pos;        // scattered 4B
}

// ---------------- h0 = edge_attr * imp, bf16, SORTED order --------------------
__global__ __launch_bounds__(256) void kprep0(const float* __restrict__ ea,
                                              const int* __restrict__ orig,
                                              const float* __restrict__ recf, // (const float*)rec
                                              u16* __restrict__ h0, int E){
  int idx = blockIdx.x*256 + threadIdx.x;
  int row = idx >> 2;
  int c   = (idx & 3)*8;
  if(row >= E) return;
  int oe = orig[row];
  float ie = recf[(size_t)row*4 + 3];           // ERec.ie
  const float* s = ea + (size_t)oe*32 + c;
  f32x4 v0 = *(const f32x4*)s;
  f32x4 v1 = *(const f32x4*)(s+4);
  u32 o0 = (u32)f2bf(v0.x*ie) | ((u32)f2bf(v0.y*ie) << 16);
  u32 o1 = (u32)f2bf(v0.z*ie) | ((u32)f2bf(v0.w*ie) << 16);
  u32 o2 = (u32)f2bf(v1.x*ie) | ((u32)f2bf(v1.y*ie) << 16);
  u32 o3 = (u32)f2bf(v1.z*ie) | ((u32)f2bf(v1.w*ie) << 16);
  *(uint4*)(h0 + (size_t)row*32 + c) = make_uint4(o0,o1,o2,o3);
}

// ---------------- W -> fragment-ready layout (all 3 layers, one launch) -------
__global__ void kprepw(const float* __restrict__ W0, u16* __restrict__ wf0,
                       const float* __restrict__ W1, u16* __restrict__ wf1,
                       const float* __restrict__ W2, u16* __restrict__ wf2){
  const int b = blockIdx.x;
  const float* W; u16* wf; int NC, sbase;
  if(b == 0){ W = W0; wf = wf0; NC = 1; sbase = 0; }
  else if(b <= 2){ W = W1; wf = wf1; NC = 2; sbase = (b-1)*256; }
  else { W = W2; wf = wf2; NC = 2; sbase = (b-3)*256; }
  int s = sbase + threadIdx.x;
  if(s >= 4*NC*64) return;
  int lane = s & 63;
  int c    = (s >> 6) % NC;
  int tt   = s / (NC*64);
  int n  = tt*16 + (lane & 15);
  int k0 = c*32 + (lane >> 4)*8;
  #pragma unroll
  for(int j = 0; j < 8; j++)
    wf[(size_t)s*8 + j] = f2bf(W[(size_t)(k0 + j)*64 + n]);
}

// ---------------- aggregate (templated on row dim) ----------------------------
template<int DIM>
__global__ __launch_bounds__(256) void kagg(const u16* __restrict__ buf,
                                            const int* __restrict__ off0,
                                            const int* __restrict__ off1,
                                            const int* __restrict__ list1,
                                            u16* __restrict__ heb, int N){
  const int t = threadIdx.x, wv = t >> 6, lane = t & 63;
  const int n = blockIdx.x*4 + wv;
  if(n >= N) return;
  constexpr int CB = DIM/8;       // col-blocks (8 cols each)
  constexpr int RS = 64/CB;       // rows per wave-instr
  const int rsub = lane / CB, cb = lane % CB;
  float acc[8];
  #pragma unroll
  for(int k = 0; k < 8; k++) acc[k] = 0.f;

  auto accum = [&](uint4 x){
    acc[0] += bf2f((u16)x.x); acc[1] += bf2f((u16)(x.x>>16));
    acc[2] += bf2f((u16)x.y); acc[3] += bf2f((u16)(x.y>>16));
    acc[4] += bf2f((u16)x.z); acc[5] += bf2f((u16)(x.z>>16));
    acc[6] += bf2f((u16)x.w); acc[7] += bf2f((u16)(x.w>>16));
  };
  const uint4 zero4 = {0,0,0,0};

  // u-side: contiguous rows [off0[n], off0[n+1])
  {
    const int s0 = off0[n], d0 = off0[n+1] - s0;
    const u16* base = buf + (size_t)s0*DIM;
    int j = 0;
    for(; j + RS <= d0; j += RS)
      accum(*(const uint4*)(base + (size_t)(j+rsub)*DIM + cb*8));
    if(j < d0)
      accum((rsub < d0-j) ? *(const uint4*)(base + (size_t)(j+rsub)*DIM + cb*8) : zero4);
  }
  // v-side: random rows via list1
  {
    const int s1 = off1[n], d1 = off1[n+1] - s1;
    int j = 0;
    for(; j + RS <= d1; j += RS){
      int e = list1[s1 + j + rsub];
      accum(*(const uint4*)(buf + (size_t)e*DIM + cb*8));
    }
    if(j < d1){
      uint4 x = zero4;
      if(rsub < d1-j){
        int e = list1[s1 + j + rsub];
        x = *(const uint4*)(buf + (size_t)e*DIM + cb*8);
      }
      accum(x);
    }
  }
  // reduce across rsub
  #pragma unroll
  for(int m = CB; m <= 32; m <<= 1)
    #pragma unroll
    for(int k = 0; k < 8; k++) acc[k] += __shfl_xor(acc[k], m);
  if(rsub == 0){
    u32 o[4];
    #pragma unroll
    for(int k = 0; k < 4; k++)
      o[k] = (u32)f2bf(acc[2*k]) | ((u32)f2bf(acc[2*k+1]) << 16);
    *(uint4*)(heb + (size_t)n*DIM + cb*8) = make_uint4(o[0],o[1],o[2],o[3]);
  }
}

// ---------------- layer 1 fused: combine(32) -> @W0 -> epilogue -> @W1 --------
// ROW-OWNERSHIP gathers/combine: lane owns row lane>>2, cols (lane&3)*8..+8.
// 3x 16-B loads + 4 bpermutes + 8 vector FMAs + 1 ds_write_b128 per group.
__global__ __launch_bounds__(256, 3) void kfusedR1(const u16* __restrict__ h0,
                                                   const u16* __restrict__ agg0,
                                                   u16* __restrict__ buf,
                                                   const f32x4* __restrict__ rec4,
                                                   const int* __restrict__ batch,
                                                   const float* __restrict__ bias0,
                                                   const u16* __restrict__ wf0,
                                                   const u16* __restrict__ wf1,
                                                   float* __restrict__ gh0,
                                                   int E){
  __shared__ __align__(16) u16 hT[4*16*72];
  __shared__ float ies[4][16];
  const int t = threadIdx.x, wv = t >> 6, lane = t & 63;
  const int quad = lane >> 4, l15 = lane & 15;
  const int rowq = lane >> 2;         // row owned in gather/combine (0..15)
  const int cb8  = (lane & 3) * 8;    // col offset within the 32-dim row
  u16* hTw = &hT[wv*1152];

  float bd4[4];
  #pragma unroll
  for(int tt = 0; tt < 4; tt++) bd4[tt] = bias0[tt*16 + l15];

  bf16x8 b0fr[4];
  #pragma unroll
  for(int i = 0; i < 4; i++)
    b0fr[i] = *(const bf16x8*)(wf0 + ((size_t)i*64 + lane)*8);
  bf16x8 b1fr[8];
  #pragma unroll
  for(int i = 0; i < 8; i++)
    b1fr[i] = *(const bf16x8*)(wf1 + ((size_t)i*64 + lane)*8);

  float pool[4] = {0.f,0.f,0.f,0.f};
  int cur_g = -1;
  const int base = __builtin_amdgcn_readfirstlane((int)(blockIdx.x*256) + wv*64);

  auto flushPool = [&](){
    #pragma unroll
    for(int tt = 0; tt < 4; tt++){
      float s = pool[tt];
      s += __shfl_xor(s, 16);
      s += __shfl_xor(s, 32);
      if(quad == 0) atomAddF(&gh0[cur_g*192 + tt*16 + l15], s);
      pool[tt] = 0.f;
    }
  };

  // descriptor bank: lane l15 holds edge base+l15
  u32 uvp = 0; f32x4 cf = {0.f,0.f,0.f,0.f}; int bt = 0;
  if(base < E){
    f32x4 w0 = rec4[(size_t)(base+l15)];
    uvp = __float_as_uint(w0.x);
    const float iu = w0.y, iv = w0.z;
    const float rc = (iu > 0.f && iv > 0.f) ? (1.f/3.f)
                   : ((iu > 0.f || iv > 0.f) ? 0.5f : 1.f);
    cf.x = rc; cf.y = iu*rc; cf.z = iv*rc; cf.w = w0.w;
    bt  = batch[uvp & 0xffffu];
  }

  #pragma unroll 1
  for(int it = 0; it < 4; it++){
    const int r0 = base + it*16;
    if(r0 < E){
      // ---- row-ownership gathers: 3x 16-B loads per lane ----
      const u32 uvr = (u32)__shfl((int)uvp, rowq);   // bpermute
      bf16x8 zb8 = *(const bf16x8*)(h0  + (size_t)(r0 + rowq)*32 + cb8);
      bf16x8 hu8 = *(const bf16x8*)(agg0 + (size_t)(uvr & 0xffffu)*32 + cb8);
      bf16x8 hv8 = *(const bf16x8*)(agg0 + (size_t)(uvr >> 16)*32 + cb8);
      const float rcr = __shfl(cf.x, rowq);
      const float iur = __shfl(cf.y, rowq);
      const float ivr = __shfl(cf.z, rowq);
      // ---- prefetch next group's descriptors ----
      u32 uvpN = uvp; f32x4 cfN = cf; int btN = bt;
      if(it < 3){
        const int r1 = r0 + 16;
        if(r1 < E){
          f32x4 w0 = rec4[(size_t)(r1+l15)];
          uvpN = __float_as_uint(w0.x);
          const float iu = w0.y, iv = w0.z;
          const float rc = (iu > 0.f && iv > 0.f) ? (1.f/3.f)
                         : ((iu > 0.f || iv > 0.f) ? 0.5f : 1.f);
          cfN.x = rc; cfN.y = iu*rc; cfN.z = iv*rc; cfN.w = w0.w;
          btN  = batch[uvpN & 0xffffu];
        }
      }
      // ---- publish ie per row for fragment epilogue ----
      if(lane < 16) ies[wv][lane] = cf.w;
      // ---- combine -> z (bf16), one 16-B ds_write per lane ----
      u16 zw[8];
      #pragma unroll
      for(int j = 0; j < 8; j++){
        float z = fmaf(bf2f((u16)zb8[j]), rcr,
                  fmaf(bf2f((u16)hu8[j]), iur, bf2f((u16)hv8[j])*ivr));
        zw[j] = f2bf(z);
      }
      *(bf16x8*)&hTw[rowq*72 + cb8] = *(const bf16x8*)zw;
      // ---- MFMA1: z @ W0 (K=32) ----
      bf16x8 za = *(const bf16x8*)&hTw[l15*72 + quad*8];
      f32x4 a0_[4];
      #pragma unroll
      for(int tt = 0; tt < 4; tt++){
        f32x4 a = {0.f,0.f,0.f,0.f};
        a = __builtin_amdgcn_mfma_f32_16x16x32_bf16(za, b0fr[tt], a, 0, 0, 0);
        a0_[tt] = a;
      }
      // ---- fragment epilogue: h1 = relu(a + b0) * ie[row] ----
      float ier[4];
      #pragma unroll
      for(int r = 0; r < 4; r++) ier[r] = ies[wv][quad*4 + r];
      float o[4][4];
      #pragma unroll
      for(int tt = 0; tt < 4; tt++)
        #pragma unroll
        for(int r = 0; r < 4; r++)
          o[tt][r] = fmaxf(a0_[tt][r] + bd4[tt], 0.f) * ier[r];
      // ---- pool gh0 ----
      const int bFirst = __builtin_amdgcn_readlane(bt, 0);
      const int bLast  = __builtin_amdgcn_readlane(bt, 15);
      if(bFirst == bLast){
        if(bFirst != cur_g){
          if(cur_g >= 0) flushPool();
          cur_g = bFirst;
        }
        #pragma unroll
        for(int tt = 0; tt < 4; tt++)
          pool[tt] += (o[tt][0] + o[tt][1]) + (o[tt][2] + o[tt][3]);
      } else {
        #pragma unroll
        for(int rr = 0; rr < 16; rr++){
          const int bq = __builtin_amdgcn_readlane(bt, rr);
          if(bq != cur_g){
            if(cur_g >= 0) flushPool();
            cur_g = bq;
          }
          if((rr >> 2) == quad){
            #pragma unroll
            for(int tt = 0; tt < 4; tt++) pool[tt] += o[tt][rr & 3];
          }
        }
      }
      // ---- h1 -> LDS [16][72] full 64 cols ----
      #pragma unroll
      for(int tt = 0; tt < 4; tt++)
        #pragma unroll
        for(int r = 0; r < 4; r++)
          hTw[(quad*4 + r)*72 + tt*16 + l15] = f2bf(o[tt][r]);
      // ---- MFMA2: h1 @ W1 (K=64) -> buf (xw2) ----
      bf16x8 afr0 = *(const bf16x8*)&hTw[l15*72 + quad*8];
      bf16x8 afr1 = *(const bf16x8*)&hTw[l15*72 + 32 + quad*8];
      #pragma unroll
      for(int tt = 0; tt < 4; tt++){
        f32x4 a = {0.f,0.f,0.f,0.f};
        a = __builtin_amdgcn_mfma_f32_16x16x32_bf16(afr0, b1fr[tt*2+0], a, 0, 0, 0);
        a = __builtin_amdgcn_mfma_f32_16x16x32_bf16(afr1, b1fr[tt*2+1], a, 0, 0, 0);
        const int n = tt*16 + l15;
        #pragma unroll
        for(int r = 0; r < 4; r++)
          buf[(size_t)(r0 + quad*4 + r)*64 + n] = f2bf(a[r]);
      }
      uvp = uvpN; cf = cfN; bt = btN;
    }
  }
  if(cur_g >= 0) flushPool();
}

// ---------------- fused L2/L3: gather + epilogue + register-pool (+ GEMM) -----
template<bool DO_GEMM>
__global__ __launch_bounds__(256, 3) void kfused(u16* __restrict__ buf,   // r/w
                                                 const u16* __restrict__ heb,
                                                 const f32x4* __restrict__ rec4,
                                                 const int* __restrict__ batch,
                                                 const float* __restrict__ bias,
                                                 const u16* __restrict__ wf,
                                                 float* __restrict__ ghL,
                                                 int E){
  constexpr int HTSZ = DO_GEMM ? 4*16*72 : 4;
  __shared__ __align__(16) u16 hT[HTSZ];
  const int t = threadIdx.x, wv = t >> 6, lane = t & 63;
  const int quad = lane >> 4, l15 = lane & 15;
  const float bd = bias[lane];

  bf16x8 bfr[8];
  if(DO_GEMM){
    #pragma unroll
    for(int i = 0; i < 8; i++)
      bfr[i] = *(const bf16x8*)(wf + ((size_t)i*64 + lane)*8);
  }

  float pool = 0.f;
  int cur_g = -1;
  const int base = __builtin_amdgcn_readfirstlane((int)(blockIdx.x*256) + wv*64);
  u16* hTw = DO_GEMM ? &hT[wv*1152] : &hT[0];

  u32 uvp = 0; f32x4 cf = {0.f,0.f,0.f,0.f}; int bt = 0;
  if(base < E){
    f32x4 w0 = rec4[(size_t)(base+l15)];
    uvp = __float_as_uint(w0.x);
    const float iu = w0.y, iv = w0.z;
    const float rc = (iu > 0.f && iv > 0.f) ? (1.f/3.f)
                   : ((iu > 0.f || iv > 0.f) ? 0.5f : 1.f);
    cf.x = rc; cf.y = iu*rc; cf.z = iv*rc; cf.w = w0.w;
    bt  = batch[uvp & 0xffffu];
  }

  #pragma unroll
  for(int it = 0; it < 4; it++){
    const int r0 = base + it*16;
    if(r0 < E){
      u16 bv[16], hu[16], hv[16];
      const u16* bufr = buf + (size_t)r0*64;
      #pragma unroll
      for(int q = 0; q < 16; q++){
        const u32 uv = (u32)__builtin_amdgcn_readlane((int)uvp, q);
        hv[q] = heb[(size_t)(uv >> 16)*64 + lane];
        hu[q] = heb[(size_t)(uv & 0xffffu)*64 + lane];
        bv[q] = bufr[q*64 + lane];
      }
      u32 uvpN = uvp; f32x4 cfN = cf; int btN = bt;
      if(it < 3){
        const int r1 = r0 + 16;
        if(r1 < E){
          f32x4 w0 = rec4[(size_t)(r1+l15)];
          uvpN = __float_as_uint(w0.x);
          const float iu = w0.y, iv = w0.z;
          const float rc = (iu > 0.f && iv > 0.f) ? (1.f/3.f)
                         : ((iu > 0.f || iv > 0.f) ? 0.5f : 1.f);
          cfN.x = rc; cfN.y = iu*rc; cfN.z = iv*rc; cfN.w = w0.w;
          btN  = batch[uvpN & 0xffffu];
        }
      }
      const int bFirst = __builtin_amdgcn_readlane(bt, 0);
      const int bLast  = __builtin_amdgcn_readlane(bt, 15);
      if(bFirst != cur_g){
        if(cur_g >= 0) atomAddF(&ghL[cur_g*192 + lane], pool);
        pool = 0.f; cur_g = bFirst;
      }
      if(bFirst == bLast){
        #pragma unroll
        for(int q = 0; q < 16; q++){
          const float rc   = rlanef(cf.x, q);
          const float iurc = rlanef(cf.y, q);
          const float ivrc = rlanef(cf.z, q);
          const float ie   = rlanef(cf.w, q);
          float o = fmaxf(fmaf(bf2f(bv[q]), rc,
                          fmaf(bf2f(hu[q]), iurc,
                          fmaf(bf2f(hv[q]), ivrc, bd))), 0.f) * ie;
          pool += o;
          if(DO_GEMM) hTw[q*72 + lane] = f2bf(o);
        }
      } else {
        #pragma unroll
        for(int q = 0; q < 16; q++){
          const float rc   = rlanef(cf.x, q);
          const float iurc = rlanef(cf.y, q);
          const float ivrc = rlanef(cf.z, q);
          const float ie   = rlanef(cf.w, q);
          const int   bq   = __builtin_amdgcn_readlane(bt, q);
          float o = fmaxf(fmaf(bf2f(bv[q]), rc,
                          fmaf(bf2f(hu[q]), iurc,
                          fmaf(bf2f(hv[q]), ivrc, bd))), 0.f) * ie;
          if(bq != cur_g){
            if(cur_g >= 0) atomAddF(&ghL[cur_g*192 + lane], pool);
            pool = 0.f; cur_g = bq;
          }
          pool += o;
          if(DO_GEMM) hTw[q*72 + lane] = f2bf(o);
        }
      }
      if(DO_GEMM){
        bf16x8 afr0 = *(const bf16x8*)&hTw[l15*72 + quad*8];
        bf16x8 afr1 = *(const bf16x8*)&hTw[l15*72 + 32 + quad*8];
        #pragma unroll
        for(int tt = 0; tt < 4; tt++){
          f32x4 a = {0.f,0.f,0.f,0.f};
          a = __builtin_amdgcn_mfma_f32_16x16x32_bf16(afr0, bfr[tt*2+0], a, 0, 0, 0);
          a = __builtin_amdgcn_mfma_f32_16x16x32_bf16(afr1, bfr[tt*2+1], a, 0, 0, 0);
          const int n = tt*16 + l15;
          #pragma unroll
          for(int r = 0; r < 4; r++)
            buf[(size_t)(r0 + quad*4 + r)*64 + n] = f2bf(a[r]);
        }
      }
      uvp = uvpN; cf = cfN; bt = btN;
    }
  }
  if(cur_g >= 0) atomAddF(&ghL[cur_g*192 + lane], pool);
}

__global__ void kfinal(const float* __restrict__ gh, float* __restrict__ out, int n){
  int i = blockIdx.x*blockDim.x + threadIdx.x;
  if(i < n) out[i] = gh[i];   // reference output dtype = float32
}

// ---------------- host ----------------
extern "C" void kernel_launch(void* const* d_in, const int* in_sizes, int n_in,
                              void* d_out, int out_size, void* d_ws, size_t ws_size,
                              hipStream_t stream) {
  const float* edge_attr = (const float*)d_in[1];
  const int*   ei        = (const int*)d_in[2];
  const int*   batch     = (const int*)d_in[3];
  const float* nimp      = (const float*)d_in[4];
  const float* Ws[3] = { (const float*)d_in[5], (const float*)d_in[7], (const float*)d_in[9] };
  const float* bs[3] = { (const float*)d_in[6], (const float*)d_in[8], (const float*)d_in[10] };

  const int E = in_sizes[1] / 32;   // edge_attr is (E, 32)
  const int N = in_sizes[4];        // node_imp is (N,)
  const int* ei0 = ei;
  const int* ei1 = ei + E;

  char* p = (char*)d_ws;
  auto carve = [&](size_t bytes)->char*{
    char* r = p; p += (bytes + 255) & ~(size_t)255; return r;
  };
  const int nt = (N + 255)/256;
  int*   deg0c = (int*)  carve((size_t)2*NCOPY*N*4);
  int*   deg1c = deg0c + NCOPY*N;
  int*   cb0   = (int*)  carve((size_t)2*NCOPY*N*4);
  int*   cb1   = cb0 + NCOPY*N;
  int*   r0    = (int*)  carve((size_t)2*E*4);       // per-edge ranks
  int*   r1    = r0 + E;
  int*   deg0  = (int*)  carve((size_t)2*N*4);
  int*   deg1  = deg0 + N;
  NRec*  nrec  = (NRec*) carve((size_t)N*sizeof(NRec));
  int*   off0  = (int*)  carve((size_t)(N+1)*4);
  int*   off1  = (int*)  carve((size_t)(N+1)*4);
  int*   tsum  = (int*)  carve((size_t)2*nt*4);
  int*   orig  = (int*)  carve((size_t)E*4);
  int*   list1 = (int*)  carve((size_t)E*4);
  ERec*  rec   = (ERec*) carve((size_t)E*sizeof(ERec));
  u16*   h0    = (u16*)  carve((size_t)E*32*2);      // layer-1 input, sorted
  u16*   agg0  = (u16*)  carve((size_t)N*32*2);
  u16*   heb   = (u16*)  carve((size_t)N*64*2);
  u16*   buf   = (u16*)  carve((size_t)E*64*2);      // xw2 / xw3 in-place
  float* gh    = (float*)carve((size_t)64*192*4);
  u16*   wfs[3];
  for(int l = 0; l < 3; l++) wfs[l] = (u16*)carve((size_t)4096*2);

  kzero<<<(2*NCOPY*N+255)/256, 256, 0, stream>>>(deg0c, 2*NCOPY*N);
  kzero<<<(12288+255)/256, 256, 0, stream>>>((int*)gh, 12288);
  kdeg2p<<<(E+255)/256, 256, 0, stream>>>(ei0, ei1, deg0c, deg1c, r0, r1, N, E);
  kreduce<<<(2*N+255)/256, 256, 0, stream>>>(deg0c, deg1c, deg0, deg1, cb0, cb1, N);
  ktilesum<<<2*nt, 256, 0, stream>>>(deg0, deg1, tsum, N, nt);
  kmid<<<2, 256, 0, stream>>>(tsum, off0, off1, N, nt);
  kapply<<<2*nt, 256, 0, stream>>>(deg0, deg1, tsum, off0, off1, nimp, nrec, N, nt);
  kpermv<<<(E+255)/256, 256, 0, stream>>>(ei0, ei1, nrec, off0, off1, cb0, cb1,
                                          r0, r1, rec, orig, list1, E, N);
  kprep0<<<((E*4)+255)/256, 256, 0, stream>>>(edge_attr, orig, (const float*)rec, h0, E);
  kprepw<<<5, 256, 0, stream>>>(Ws[0], wfs[0], Ws[1], wfs[1], Ws[2], wfs[2]);

  const int nbA = (N + 3)/4;
  const int nbF = (E + 255)/256;   // contiguous 256-edge chunk per block

  kagg<32><<<nbA, 256, 0, stream>>>(h0, off0, off1, list1, agg0, N);
  kfusedR1<<<nbF, 256, 0, stream>>>(h0, agg0, buf, (const f32x4*)rec, batch,
                                    bs[0], wfs[0], wfs[1], gh + 0*64, E);
  kagg<64><<<nbA, 256, 0, stream>>>(buf, off0, off1, list1, heb, N);
  kfused<true ><<<nbF, 256, 0, stream>>>(buf, heb, (const f32x4*)rec, batch, bs[1], wfs[2], gh + 1*64, E);
  kagg<64><<<nbA, 256, 0, stream>>>(buf, off0, off1, list1, heb, N);
  kfused<false><<<nbF, 256, 0, stream>>>(buf, heb, (const f32x4*)rec, batch, bs[2], nullptr, gh + 2*64, E);
  kfinal<<<(12288+255)/256, 256, 0, stream>>>(gh, (float*)d_out, 12288);
}